// Round 22
// baseline (250.082 us; speedup 1.0000x reference)
//
#include <hip/hip_runtime.h>
#include <math.h>

#define N_RELS 1315
#define NB 65536
#define NNZV (1 << 20)
#define FEATD 768

#define NBUK 256       // row buckets (256 rows each)
#define CAP  4608      // bin capacity per (matrix,bucket)
#define FPT  9         // CAP/512 per-thread edges in k_fuse

typedef float f32x4 __attribute__((ext_vector_type(4)));
typedef short s16x8 __attribute__((ext_vector_type(8)));
typedef float v2f  __attribute__((ext_vector_type(2)));

struct Mats { const int* rows[6]; const int* cols[6]; const float* vals[6]; };

__device__ __forceinline__ short f2bf(float f) {
    return __builtin_bit_cast(short, (__bf16)f);
}

// ---------------- precompute: P tables, Prel, b' (+ cursor init) ----------------
__global__ void k_prep(const float* __restrict__ rel_emb,
                       const float* __restrict__ W_in, const float* __restrict__ b_in,
                       const float* __restrict__ W_out, const float* __restrict__ b_out,
                       const float* __restrict__ W_ent, const float* __restrict__ b_ent,
                       const float* __restrict__ W_rel, const float* __restrict__ b_rel,
                       float* __restrict__ Pcat, float* __restrict__ Prel,
                       float* __restrict__ bprime, unsigned* __restrict__ cursor)
{
    __shared__ float C[2][32][33];
    const int tid = threadIdx.x;
    if (cursor != nullptr && blockIdx.x < 6) {
        const int i = blockIdx.x * 256 + tid;
        cursor[i] = (unsigned)i * CAP;
    }
    for (int idx = tid; idx < 2 * 32 * 32; idx += 256) {
        int d = idx >> 10, o = (idx >> 5) & 31, t = idx & 31;
        const float* W  = d ? W_out : W_in;
        const float* we = W_ent + o * 832 + 768 + d * 32;
        float s = 0.f;
        #pragma unroll
        for (int j = 0; j < 32; ++j) s += we[j] * W[j * 32 + t];
        C[d][o][t] = s;
    }
    __syncthreads();

    const int row8 = blockIdx.x * 8 + (tid >> 5);
    const int o = tid & 31;
    if (row8 < 2 * N_RELS) {
        const int d = (row8 >= N_RELS) ? 1 : 0;
        const int r = row8 - d * N_RELS;
        const float* re = rel_emb + r * 32;
        float s = 0.f;
        #pragma unroll
        for (int t = 0; t < 32; ++t) s += re[t] * C[d][o][t];
        Pcat[row8 * 32 + o] = s;
    } else if (row8 < 3 * N_RELS) {
        const int r = row8 - 2 * N_RELS;
        const float* re = rel_emb + r * 32;
        float s = b_rel[o];
        #pragma unroll
        for (int j = 0; j < 32; ++j) s += W_rel[o * 32 + j] * re[j];
        float sq = s * s;
        #pragma unroll
        for (int m = 16; m; m >>= 1) sq += __shfl_xor(sq, m);
        Prel[r * 32 + o] = s / fmaxf(sqrtf(sq), 1e-12f);
    }
    if (blockIdx.x == 0 && tid < 32) {
        float s = b_ent[tid];
        #pragma unroll
        for (int j = 0; j < 32; ++j)
            s += b_in[j] * W_ent[tid * 832 + 768 + j] + b_out[j] * W_ent[tid * 832 + 800 + j];
        bprime[tid] = s;
    }
}

// ---------------- pack W_ent[:, :768] into bf16 B-fragments ----------------
__global__ void k_wfrag(const float* __restrict__ W_ent, s16x8* __restrict__ wsB)
{
    const int t = blockIdx.x * 256 + threadIdx.x;
    if (t >= 24 * 2 * 64) return;
    const int kk = t >> 7, rem = t & 127, nt = rem >> 6, l = rem & 63;
    const int col = nt * 16 + (l & 15);
    const int k0  = kk * 32 + ((l >> 4) << 3);
    const float* w = W_ent + col * 832 + k0;
    s16x8 v;
    #pragma unroll
    for (int e = 0; e < 8; ++e) v[e] = f2bf(w[e]);
    wsB[t] = v;
}

// ---------------- bin v3: LDS-sorted stage, coalesced run writes ----------------
__global__ __launch_bounds__(512) void k_bin(Mats m, uint2* __restrict__ bins,
                                             unsigned* __restrict__ cursor)
{
    __shared__ uint2 stage[4096];     // 32 KB
    __shared__ int hist[256], sc[256], ofs[256];
    __shared__ unsigned gbase[256];
    const int bi    = blockIdx.x;     // 0..1535 = 6 matrices x 256 chunks
    const int mm    = bi >> 8;
    const int chunk = bi & 255;
    const int tid   = threadIdx.x;
    const int* __restrict__ R = m.rows[mm];
    const int* __restrict__ C = m.cols[mm];
    const float* __restrict__ V = m.vals[mm];
    const int base = chunk * 4096;

    if (tid < 256) hist[tid] = 0;
    __syncthreads();

    unsigned meta[8]; float val[8]; unsigned short lrank[8];
    #pragma unroll
    for (int e = 0; e < 8; ++e) {
        const int idx = base + e * 512 + tid;
        const int row = R[idx];
        const int col = C[idx];
        val[e]  = V[idx];
        meta[e] = ((unsigned)row << 11) | (unsigned)col;     // 27 bits; buk = >>19
        lrank[e] = (unsigned short)atomicAdd(&hist[meta[e] >> 19], 1);
    }
    __syncthreads();

    if (tid < 256) sc[tid] = hist[tid];
    __syncthreads();
    for (int off = 1; off < 256; off <<= 1) {
        const int x = (tid >= off && tid < 256) ? sc[tid - off] : 0;
        __syncthreads();
        if (tid < 256) sc[tid] += x;
        __syncthreads();
    }
    if (tid < 256) {
        ofs[tid]   = tid ? sc[tid - 1] : 0;
        gbase[tid] = atomicAdd(&cursor[mm * NBUK + tid], hist[tid]);
    }
    __syncthreads();

    #pragma unroll
    for (int e = 0; e < 8; ++e)
        stage[ofs[meta[e] >> 19] + lrank[e]] = make_uint2(meta[e], __float_as_uint(val[e]));
    __syncthreads();

    #pragma unroll
    for (int e = 0; e < 8; ++e) {
        const int i = e * 512 + tid;
        const uint2 ed = stage[i];
        const unsigned buk = ed.x >> 19;
        bins[gbase[buk] + (unsigned)(i - ofs[buk])] = make_uint2(ed.x & 0x7FFFFu, ed.y);
    }
}

// ---------------- fused bucket sort + gather: aggY[set][rows of bucket] ----------
// v2: 2-edge-unrolled row walk (both P-load batches in flight).
__global__ __launch_bounds__(512) void k_fuse(const uint2* __restrict__ bins,
                                              const unsigned* __restrict__ cursor,
                                              const float* __restrict__ Pcat,
                                              float* __restrict__ aggY)
{
    __shared__ uint2 stage[CAP];      // 36,864 B
    __shared__ int hist[256], sc[256], ofs[256];
    const int set = blockIdx.x >> 8;  // 3 sets x 256 buckets
    const int b   = blockIdx.x & 255;
    const int t   = threadIdx.x;
    const int row  = t >> 1;          // local row 0..255
    const int half = t & 1;           // comp half (16 each)

    float acc[16];
    #pragma unroll
    for (int j = 0; j < 16; ++j) acc[j] = 0.f;

    for (int dir = 0; dir < 2; ++dir) {
        const int mb = (set * 2 + dir) * NBUK + b;
        const unsigned segbase = (unsigned)mb * CAP;
        const uint2* __restrict__ seg = bins + segbase;
        const int len = (int)(cursor[mb] - segbase);
        const float* __restrict__ P = Pcat + (size_t)dir * N_RELS * 32;

        if (t < 256) hist[t] = 0;
        __syncthreads();

        uint2 e[FPT];
        #pragma unroll
        for (int j = 0; j < FPT; ++j) {
            const int i = t + j * 512;
            if (i < len) e[j] = seg[i];
        }
        #pragma unroll
        for (int j = 0; j < FPT; ++j) {
            const int i = t + j * 512;
            if (i < len) atomicAdd(&hist[e[j].x >> 11], 1);
        }
        __syncthreads();

        if (t < 256) sc[t] = hist[t];
        __syncthreads();
        for (int off = 1; off < 256; off <<= 1) {
            const int x = (t >= off && t < 256) ? sc[t - off] : 0;
            __syncthreads();
            if (t < 256) sc[t] += x;
            __syncthreads();
        }
        if (t < 256) ofs[t] = t ? sc[t - 1] : 0;
        __syncthreads();
        const int myo = row ? sc[row - 1] : 0;
        const int myc = hist[row];

        #pragma unroll
        for (int j = 0; j < FPT; ++j) {
            const int i = t + j * 512;
            if (i < len) {
                const int pos = atomicAdd(&ofs[e[j].x >> 11], 1);
                stage[pos] = make_uint2(e[j].x & 2047u, e[j].y);
            }
        }
        __syncthreads();

        // 2-edge unrolled row walk: two independent P-load batches in flight
        int j = 0;
        for (; j + 2 <= myc; j += 2) {
            const uint2 e0 = stage[myo + j];
            const uint2 e1 = stage[myo + j + 1];
            const float v0 = __uint_as_float(e0.y);
            const float v1 = __uint_as_float(e1.y);
            const float4* pr0 = reinterpret_cast<const float4*>(P + (e0.x << 5) + half * 16);
            const float4* pr1 = reinterpret_cast<const float4*>(P + (e1.x << 5) + half * 16);
            float4 p0[4], p1[4];
            #pragma unroll
            for (int q = 0; q < 4; ++q) { p0[q] = pr0[q]; p1[q] = pr1[q]; }
            #pragma unroll
            for (int q = 0; q < 4; ++q) {
                acc[q * 4 + 0] += v0 * p0[q].x + v1 * p1[q].x;
                acc[q * 4 + 1] += v0 * p0[q].y + v1 * p1[q].y;
                acc[q * 4 + 2] += v0 * p0[q].z + v1 * p1[q].z;
                acc[q * 4 + 3] += v0 * p0[q].w + v1 * p1[q].w;
            }
        }
        if (j < myc) {
            const uint2 e0 = stage[myo + j];
            const float v0 = __uint_as_float(e0.y);
            const float4* pr0 = reinterpret_cast<const float4*>(P + (e0.x << 5) + half * 16);
            float4 p0[4];
            #pragma unroll
            for (int q = 0; q < 4; ++q) p0[q] = pr0[q];
            #pragma unroll
            for (int q = 0; q < 4; ++q) {
                acc[q * 4 + 0] += v0 * p0[q].x;
                acc[q * 4 + 1] += v0 * p0[q].y;
                acc[q * 4 + 2] += v0 * p0[q].z;
                acc[q * 4 + 3] += v0 * p0[q].w;
            }
        }
        __syncthreads();
    }

    float4* dst = reinterpret_cast<float4*>(
        aggY + ((size_t)set * NB + (size_t)b * 256 + row) * 32 + half * 16);
    #pragma unroll
    for (int q = 0; q < 4; ++q) {
        float4 wv;
        wv.x = acc[q * 4 + 0]; wv.y = acc[q * 4 + 1];
        wv.z = acc[q * 4 + 2]; wv.w = acc[q * 4 + 3];
        dst[q] = wv;
    }
}

// ---------------- fallback scatter (ws too small) ----------------
__global__ void k_scatter(const int* __restrict__ rows, const int* __restrict__ cols,
                          const float* __restrict__ vals,
                          const float* __restrict__ Ptab, float* __restrict__ accs)
{
    const int stride = gridDim.x * blockDim.x;
    const int total = NNZV << 4;
    for (int g = blockIdx.x * blockDim.x + threadIdx.x; g < total; g += stride) {
        const int c2 = (g & 15) << 1;
        const int i  = g >> 4;
        const int row = rows[i];
        const int col = cols[i];
        const float v = vals[i];
        const float* p = Ptab + (col << 5) + c2;
        const int dst = (row << 5) + c2;
#if defined(__has_builtin) && __has_builtin(__builtin_amdgcn_global_atomic_fadd_v2f32)
        typedef __attribute__((address_space(1))) v2f* v2f_as1;
        v2f pv; pv.x = v * p[0]; pv.y = v * p[1];
        __builtin_amdgcn_global_atomic_fadd_v2f32(
            (v2f_as1)(unsigned long long)(accs + dst), pv);
#else
        atomicAdd(accs + dst,     v * p[0]);
        atomicAdd(accs + dst + 1, v * p[1]);
#endif
    }
}

// ---------------- GEMM v11: 32-entity tiles (8 barrier domains/CU) + nt loads ----
// 128 threads (2 waves), 17.5 KB LDS -> 8 blocks/CU: same 16 waves/CU, 8
// independent barrier domains. nt feat loads (L3 bypass) kept.
__global__ __launch_bounds__(128) void k_gemm(
    const float* __restrict__ feat_h, const float* __restrict__ feat_p,
    const float* __restrict__ feat_n,
    const s16x8* __restrict__ wsB, const float* __restrict__ bprime,
    const float* __restrict__ aggY, const int* __restrict__ eid,
    const float* __restrict__ Prel, float* __restrict__ out)
{
    __shared__ f32x4 lA[2][32 * 17];      // 2 x 8,704 B padded A chunk dbuf
    __shared__ float lbp[32];

    const int tid  = threadIdx.x;
    const int lane = tid & 63;
    const int w    = tid >> 6;            // wave 0..1
    const int bid  = blockIdx.x;          // 0..2047
    const int tile = (bid & 7) * 256 + (bid >> 3);  // XCD-contiguous (bijective)
    const int e0   = tile << 5;           // 32 entities per block

    const int l15 = lane & 15;
    const int kq  = lane >> 4;

    if (tid < 32) lbp[tid] = bprime[tid];

    const int srow = tid >> 4;            // 0..7
    const int scol = tid & 15;            // f32x4 slot within 256B chunk-row
    const s16x8* wsl = wsB + lane;
    const int rowA = (w << 4) + l15;      // 0..31

    f32x4 aH0 = {0.f,0.f,0.f,0.f}, aH1 = {0.f,0.f,0.f,0.f};
    f32x4 aP0 = {0.f,0.f,0.f,0.f}, aP1 = {0.f,0.f,0.f,0.f};
    f32x4 aN0 = {0.f,0.f,0.f,0.f}, aN1 = {0.f,0.f,0.f,0.f};

#define NTL(P) __builtin_nontemporal_load(P)

#define GEMM_SET(FEATP, A0, A1) do { \
    const f32x4* gs0 = reinterpret_cast<const f32x4*>((FEATP) + (size_t)(e0 + srow)      * FEATD) + scol; \
    const f32x4* gs1 = reinterpret_cast<const f32x4*>((FEATP) + (size_t)(e0 + 8  + srow) * FEATD) + scol; \
    const f32x4* gs2 = reinterpret_cast<const f32x4*>((FEATP) + (size_t)(e0 + 16 + srow) * FEATD) + scol; \
    const f32x4* gs3 = reinterpret_cast<const f32x4*>((FEATP) + (size_t)(e0 + 24 + srow) * FEATD) + scol; \
    f32x4 r0 = NTL(gs0), r1 = NTL(gs1), r2 = NTL(gs2), r3 = NTL(gs3); \
    lA[0][(srow     ) * 17 + scol] = r0; \
    lA[0][(srow + 8 ) * 17 + scol] = r1; \
    lA[0][(srow + 16) * 17 + scol] = r2; \
    lA[0][(srow + 24) * 17 + scol] = r3; \
    r0 = NTL(gs0 + 16); r1 = NTL(gs1 + 16); r2 = NTL(gs2 + 16); r3 = NTL(gs3 + 16); \
    __syncthreads(); \
    for (int c = 0; c < 12; ++c) { \
        if (c < 11) { \
            lA[(c + 1) & 1][(srow     ) * 17 + scol] = r0; \
            lA[(c + 1) & 1][(srow + 8 ) * 17 + scol] = r1; \
            lA[(c + 1) & 1][(srow + 16) * 17 + scol] = r2; \
            lA[(c + 1) & 1][(srow + 24) * 17 + scol] = r3; \
            if (c < 10) { \
                r0 = NTL(gs0 + (c + 2) * 16); r1 = NTL(gs1 + (c + 2) * 16); \
                r2 = NTL(gs2 + (c + 2) * 16); r3 = NTL(gs3 + (c + 2) * 16); \
            } \
        } \
        _Pragma("unroll") \
        for (int s = 0; s < 2; ++s) { \
            const int kk = c * 2 + s; \
            const f32x4 fa0 = lA[c & 1][rowA * 17 + s * 8 + kq * 2]; \
            const f32x4 fa1 = lA[c & 1][rowA * 17 + s * 8 + kq * 2 + 1]; \
            s16x8 av; \
            av[0] = f2bf(fa0.x); av[1] = f2bf(fa0.y); av[2] = f2bf(fa0.z); av[3] = f2bf(fa0.w); \
            av[4] = f2bf(fa1.x); av[5] = f2bf(fa1.y); av[6] = f2bf(fa1.z); av[7] = f2bf(fa1.w); \
            const s16x8 wb0 = wsl[(kk * 2 + 0) << 6]; \
            const s16x8 wb1 = wsl[(kk * 2 + 1) << 6]; \
            A0 = __builtin_amdgcn_mfma_f32_16x16x32_bf16(av, wb0, A0, 0, 0, 0); \
            A1 = __builtin_amdgcn_mfma_f32_16x16x32_bf16(av, wb1, A1, 0, 0, 0); \
        } \
        __syncthreads(); \
    } \
} while (0)

    GEMM_SET(feat_h, aH0, aH1);
    GEMM_SET(feat_p, aP0, aP1);
    GEMM_SET(feat_n, aN0, aN1);

#undef GEMM_SET
#undef NTL

    const float bp0 = lbp[l15], bp1 = lbp[l15 + 16];
    const int rbase = e0 + (w << 4) + (kq << 2);

#define NORM1(A0_, A1_, SOFF, Y0_, Y1_) do { \
    float v0 = (A0_)[e] + bp0 + aggY[(SOFF) + eoff + l15]; \
    float v1 = (A1_)[e] + bp1 + aggY[(SOFF) + eoff + l15 + 16]; \
    float sq = v0 * v0 + v1 * v1; \
    sq += __shfl_xor(sq, 1); sq += __shfl_xor(sq, 2); \
    sq += __shfl_xor(sq, 4); sq += __shfl_xor(sq, 8); \
    const float inv = 1.f / fmaxf(sqrtf(sq), 1e-12f); \
    Y0_ = v0 * inv; Y1_ = v1 * inv; \
} while (0)

    #pragma unroll
    for (int e = 0; e < 4; ++e) {
        const int ent = rbase + e;
        const size_t eoff = (size_t)ent * 32;
        float yh0, yh1, yp0, yp1, yn0, yn1;
        NORM1(aH0, aH1, (size_t)0,           yh0, yh1);
        NORM1(aP0, aP1, (size_t)NB * 32,     yp0, yp1);
        NORM1(aN0, aN1, (size_t)2 * NB * 32, yn0, yn1);
        const int ev = eid[ent];
        const float r0 = Prel[(size_t)ev * 32 + l15];
        const float r1 = Prel[(size_t)ev * 32 + l15 + 16];
        const float dp0 = yh0 + r0 - yp0, dp1 = yh1 + r1 - yp1;
        const float dn0 = yh0 + r0 - yn0, dn1 = yh1 + r1 - yn1;
        float sp = dp0 * dp0 + dp1 * dp1;
        float sn = dn0 * dn0 + dn1 * dn1;
        sp += __shfl_xor(sp, 1); sn += __shfl_xor(sn, 1);
        sp += __shfl_xor(sp, 2); sn += __shfl_xor(sn, 2);
        sp += __shfl_xor(sp, 4); sn += __shfl_xor(sn, 4);
        sp += __shfl_xor(sp, 8); sn += __shfl_xor(sn, 8);
        if (l15 == 0) { out[ent] = sqrtf(sp); out[NB + ent] = sqrtf(sn); }
    }
#undef NORM1
}

extern "C" void kernel_launch(void* const* d_in, const int* in_sizes, int n_in,
                              void* d_out, int out_size, void* d_ws, size_t ws_size,
                              hipStream_t stream)
{
    const float* feat_h = (const float*)d_in[6];
    const float* feat_p = (const float*)d_in[13];
    const float* feat_n = (const float*)d_in[20];
    const int*   eid    = (const int*)d_in[21];
    const float* rel_emb = (const float*)d_in[22];
    const float* W_in  = (const float*)d_in[23];
    const float* b_in  = (const float*)d_in[24];
    const float* W_out = (const float*)d_in[25];
    const float* b_out = (const float*)d_in[26];
    const float* W_ent = (const float*)d_in[27];
    const float* b_ent = (const float*)d_in[28];
    const float* W_rel = (const float*)d_in[29];
    const float* b_rel = (const float*)d_in[30];

    char* ws = (char*)d_ws;
    const size_t AGG_B   = (size_t)3 * NB * 32 * 4;          // 25,165,824
    const size_t BINS_B  = (size_t)6 * NBUK * CAP * 8;       // 56,623,104
    const size_t CURS_B  = 8192;
    const size_t PCAT_B  = (size_t)2 * N_RELS * 32 * 4;
    const size_t PREL_B  = (size_t)N_RELS * 32 * 4;
    const size_t BPR_B   = 128;
    const size_t WSB_B   = (size_t)24 * 2 * 64 * 16;
    const bool fast = ws_size >= AGG_B + BINS_B + CURS_B
                                + PCAT_B + PREL_B + BPR_B + WSB_B;

    float* aggY = (float*)ws;
    size_t off = AGG_B;
    uint2* bins = nullptr; unsigned* cursor = nullptr;
    if (fast) {
        bins   = (uint2*)(ws + off);    off += BINS_B;
        cursor = (unsigned*)(ws + off); off += CURS_B;
    }
    float* Pcat   = (float*)(ws + off); off += PCAT_B;
    float* Prel   = (float*)(ws + off); off += PREL_B;
    float* bprime = (float*)(ws + off); off += BPR_B;
    s16x8* wsB    = (s16x8*)(ws + off);

    k_prep<<<(3 * N_RELS + 7) / 8, 256, 0, stream>>>(rel_emb, W_in, b_in, W_out, b_out,
                                                     W_ent, b_ent, W_rel, b_rel,
                                                     Pcat, Prel, bprime, cursor);
    k_wfrag<<<12, 256, 0, stream>>>(W_ent, wsB);

    static const int base_idx[6] = {0, 3, 7, 10, 14, 17};
    if (fast) {
        Mats m;
        for (int i = 0; i < 6; ++i) {
            m.rows[i] = (const int*)d_in[base_idx[i]];
            m.cols[i] = (const int*)d_in[base_idx[i] + 1];
            m.vals[i] = (const float*)d_in[base_idx[i] + 2];
        }
        k_bin<<<6 * 256, 512, 0, stream>>>(m, bins, cursor);
        k_fuse<<<3 * 256, 512, 0, stream>>>(bins, cursor, Pcat, aggY);
    } else {
        hipMemsetAsync(aggY, 0, AGG_B, stream);
        for (int mm = 0; mm < 6; ++mm) {
            const int d = mm & 1, s = mm >> 1;
            k_scatter<<<32768, 256, 0, stream>>>((const int*)d_in[base_idx[mm]],
                                                 (const int*)d_in[base_idx[mm] + 1],
                                                 (const float*)d_in[base_idx[mm] + 2],
                                                 Pcat + (size_t)d * N_RELS * 32,
                                                 aggY + (size_t)s * NB * 32);
        }
    }

    k_gemm<<<2048, 128, 0, stream>>>(feat_h, feat_p, feat_n, wsB, bprime,
                                     aggY, eid, Prel, (float*)d_out);
}

// Round 23
// 232.441 us; speedup vs baseline: 1.0759x; 1.0759x over previous
//
#include <hip/hip_runtime.h>
#include <math.h>

#define N_RELS 1315
#define NB 65536
#define NNZV (1 << 20)
#define FEATD 768

#define NBUK 256       // row buckets (256 rows each)
#define CAP  4608      // bin capacity per (matrix,bucket)
#define FPT  9         // CAP/512 per-thread edges in k_fuse

typedef float f32x4 __attribute__((ext_vector_type(4)));
typedef short s16x8 __attribute__((ext_vector_type(8)));
typedef float v2f  __attribute__((ext_vector_type(2)));

struct Mats { const int* rows[6]; const int* cols[6]; const float* vals[6]; };

__device__ __forceinline__ short f2bf(float f) {
    return __builtin_bit_cast(short, (__bf16)f);
}

// ---------------- precompute: P tables, Prel, b' (+ cursor init) ----------------
__global__ void k_prep(const float* __restrict__ rel_emb,
                       const float* __restrict__ W_in, const float* __restrict__ b_in,
                       const float* __restrict__ W_out, const float* __restrict__ b_out,
                       const float* __restrict__ W_ent, const float* __restrict__ b_ent,
                       const float* __restrict__ W_rel, const float* __restrict__ b_rel,
                       float* __restrict__ Pcat, float* __restrict__ Prel,
                       float* __restrict__ bprime, unsigned* __restrict__ cursor)
{
    __shared__ float C[2][32][33];
    const int tid = threadIdx.x;
    if (cursor != nullptr && blockIdx.x < 6) {
        const int i = blockIdx.x * 256 + tid;
        cursor[i] = (unsigned)i * CAP;
    }
    for (int idx = tid; idx < 2 * 32 * 32; idx += 256) {
        int d = idx >> 10, o = (idx >> 5) & 31, t = idx & 31;
        const float* W  = d ? W_out : W_in;
        const float* we = W_ent + o * 832 + 768 + d * 32;
        float s = 0.f;
        #pragma unroll
        for (int j = 0; j < 32; ++j) s += we[j] * W[j * 32 + t];
        C[d][o][t] = s;
    }
    __syncthreads();

    const int row8 = blockIdx.x * 8 + (tid >> 5);
    const int o = tid & 31;
    if (row8 < 2 * N_RELS) {
        const int d = (row8 >= N_RELS) ? 1 : 0;
        const int r = row8 - d * N_RELS;
        const float* re = rel_emb + r * 32;
        float s = 0.f;
        #pragma unroll
        for (int t = 0; t < 32; ++t) s += re[t] * C[d][o][t];
        Pcat[row8 * 32 + o] = s;
    } else if (row8 < 3 * N_RELS) {
        const int r = row8 - 2 * N_RELS;
        const float* re = rel_emb + r * 32;
        float s = b_rel[o];
        #pragma unroll
        for (int j = 0; j < 32; ++j) s += W_rel[o * 32 + j] * re[j];
        float sq = s * s;
        #pragma unroll
        for (int m = 16; m; m >>= 1) sq += __shfl_xor(sq, m);
        Prel[r * 32 + o] = s / fmaxf(sqrtf(sq), 1e-12f);
    }
    if (blockIdx.x == 0 && tid < 32) {
        float s = b_ent[tid];
        #pragma unroll
        for (int j = 0; j < 32; ++j)
            s += b_in[j] * W_ent[tid * 832 + 768 + j] + b_out[j] * W_ent[tid * 832 + 800 + j];
        bprime[tid] = s;
    }
}

// ---------------- pack W_ent[:, :768] into bf16 B-fragments ----------------
__global__ void k_wfrag(const float* __restrict__ W_ent, s16x8* __restrict__ wsB)
{
    const int t = blockIdx.x * 256 + threadIdx.x;
    if (t >= 24 * 2 * 64) return;
    const int kk = t >> 7, rem = t & 127, nt = rem >> 6, l = rem & 63;
    const int col = nt * 16 + (l & 15);
    const int k0  = kk * 32 + ((l >> 4) << 3);
    const float* w = W_ent + col * 832 + k0;
    s16x8 v;
    #pragma unroll
    for (int e = 0; e < 8; ++e) v[e] = f2bf(w[e]);
    wsB[t] = v;
}

// ---------------- bin v3: LDS-sorted stage, coalesced run writes ----------------
__global__ __launch_bounds__(512) void k_bin(Mats m, uint2* __restrict__ bins,
                                             unsigned* __restrict__ cursor)
{
    __shared__ uint2 stage[4096];     // 32 KB
    __shared__ int hist[256], sc[256], ofs[256];
    __shared__ unsigned gbase[256];
    const int bi    = blockIdx.x;     // 0..1535 = 6 matrices x 256 chunks
    const int mm    = bi >> 8;
    const int chunk = bi & 255;
    const int tid   = threadIdx.x;
    const int* __restrict__ R = m.rows[mm];
    const int* __restrict__ C = m.cols[mm];
    const float* __restrict__ V = m.vals[mm];
    const int base = chunk * 4096;

    if (tid < 256) hist[tid] = 0;
    __syncthreads();

    unsigned meta[8]; float val[8]; unsigned short lrank[8];
    #pragma unroll
    for (int e = 0; e < 8; ++e) {
        const int idx = base + e * 512 + tid;
        const int row = R[idx];
        const int col = C[idx];
        val[e]  = V[idx];
        meta[e] = ((unsigned)row << 11) | (unsigned)col;     // 27 bits; buk = >>19
        lrank[e] = (unsigned short)atomicAdd(&hist[meta[e] >> 19], 1);
    }
    __syncthreads();

    if (tid < 256) sc[tid] = hist[tid];
    __syncthreads();
    for (int off = 1; off < 256; off <<= 1) {
        const int x = (tid >= off && tid < 256) ? sc[tid - off] : 0;
        __syncthreads();
        if (tid < 256) sc[tid] += x;
        __syncthreads();
    }
    if (tid < 256) {
        ofs[tid]   = tid ? sc[tid - 1] : 0;
        gbase[tid] = atomicAdd(&cursor[mm * NBUK + tid], hist[tid]);
    }
    __syncthreads();

    #pragma unroll
    for (int e = 0; e < 8; ++e)
        stage[ofs[meta[e] >> 19] + lrank[e]] = make_uint2(meta[e], __float_as_uint(val[e]));
    __syncthreads();

    #pragma unroll
    for (int e = 0; e < 8; ++e) {
        const int i = e * 512 + tid;
        const uint2 ed = stage[i];
        const unsigned buk = ed.x >> 19;
        bins[gbase[buk] + (unsigned)(i - ofs[buk])] = make_uint2(ed.x & 0x7FFFFu, ed.y);
    }
}

// ---------------- fused bucket sort + gather: aggY[set][rows of bucket] ----------
__global__ __launch_bounds__(512) void k_fuse(const uint2* __restrict__ bins,
                                              const unsigned* __restrict__ cursor,
                                              const float* __restrict__ Pcat,
                                              float* __restrict__ aggY)
{
    __shared__ uint2 stage[CAP];      // 36,864 B
    __shared__ int hist[256], sc[256], ofs[256];
    const int set = blockIdx.x >> 8;  // 3 sets x 256 buckets
    const int b   = blockIdx.x & 255;
    const int t   = threadIdx.x;
    const int row  = t >> 1;          // local row 0..255
    const int half = t & 1;           // comp half (16 each)

    float acc[16];
    #pragma unroll
    for (int j = 0; j < 16; ++j) acc[j] = 0.f;

    for (int dir = 0; dir < 2; ++dir) {
        const int mb = (set * 2 + dir) * NBUK + b;
        const unsigned segbase = (unsigned)mb * CAP;
        const uint2* __restrict__ seg = bins + segbase;
        const int len = (int)(cursor[mb] - segbase);
        const float* __restrict__ P = Pcat + (size_t)dir * N_RELS * 32;

        if (t < 256) hist[t] = 0;
        __syncthreads();

        uint2 e[FPT];
        #pragma unroll
        for (int j = 0; j < FPT; ++j) {
            const int i = t + j * 512;
            if (i < len) e[j] = seg[i];
        }
        #pragma unroll
        for (int j = 0; j < FPT; ++j) {
            const int i = t + j * 512;
            if (i < len) atomicAdd(&hist[e[j].x >> 11], 1);
        }
        __syncthreads();

        if (t < 256) sc[t] = hist[t];
        __syncthreads();
        for (int off = 1; off < 256; off <<= 1) {
            const int x = (t >= off && t < 256) ? sc[t - off] : 0;
            __syncthreads();
            if (t < 256) sc[t] += x;
            __syncthreads();
        }
        if (t < 256) ofs[t] = t ? sc[t - 1] : 0;
        __syncthreads();
        const int myo = row ? sc[row - 1] : 0;
        const int myc = hist[row];

        #pragma unroll
        for (int j = 0; j < FPT; ++j) {
            const int i = t + j * 512;
            if (i < len) {
                const int pos = atomicAdd(&ofs[e[j].x >> 11], 1);
                stage[pos] = make_uint2(e[j].x & 2047u, e[j].y);
            }
        }
        __syncthreads();

        uint2 ed = (myc > 0) ? stage[myo] : make_uint2(0u, 0u);
        for (int j = 0; j < myc; ++j) {
            const uint2 nxt = (j + 1 < myc) ? stage[myo + j + 1] : make_uint2(0u, 0u);
            const float v = __uint_as_float(ed.y);
            const float4* prow = reinterpret_cast<const float4*>(P + (ed.x << 5) + half * 16);
            float4 p[4];
            #pragma unroll
            for (int q = 0; q < 4; ++q) p[q] = prow[q];
            #pragma unroll
            for (int q = 0; q < 4; ++q) {
                acc[q * 4 + 0] += v * p[q].x; acc[q * 4 + 1] += v * p[q].y;
                acc[q * 4 + 2] += v * p[q].z; acc[q * 4 + 3] += v * p[q].w;
            }
            ed = nxt;
        }
        __syncthreads();
    }

    float4* dst = reinterpret_cast<float4*>(
        aggY + ((size_t)set * NB + (size_t)b * 256 + row) * 32 + half * 16);
    #pragma unroll
    for (int q = 0; q < 4; ++q) {
        float4 wv;
        wv.x = acc[q * 4 + 0]; wv.y = acc[q * 4 + 1];
        wv.z = acc[q * 4 + 2]; wv.w = acc[q * 4 + 3];
        dst[q] = wv;
    }
}

// ---------------- fallback scatter (ws too small) ----------------
__global__ void k_scatter(const int* __restrict__ rows, const int* __restrict__ cols,
                          const float* __restrict__ vals,
                          const float* __restrict__ Ptab, float* __restrict__ accs)
{
    const int stride = gridDim.x * blockDim.x;
    const int total = NNZV << 4;
    for (int g = blockIdx.x * blockDim.x + threadIdx.x; g < total; g += stride) {
        const int c2 = (g & 15) << 1;
        const int i  = g >> 4;
        const int row = rows[i];
        const int col = cols[i];
        const float v = vals[i];
        const float* p = Ptab + (col << 5) + c2;
        const int dst = (row << 5) + c2;
#if defined(__has_builtin) && __has_builtin(__builtin_amdgcn_global_atomic_fadd_v2f32)
        typedef __attribute__((address_space(1))) v2f* v2f_as1;
        v2f pv; pv.x = v * p[0]; pv.y = v * p[1];
        __builtin_amdgcn_global_atomic_fadd_v2f32(
            (v2f_as1)(unsigned long long)(accs + dst), pv);
#else
        atomicAdd(accs + dst,     v * p[0]);
        atomicAdd(accs + dst + 1, v * p[1]);
#endif
    }
}

// ---------------- GEMM v10: 64-entity tiles (4 barrier domains/CU) + nt loads ----
// 256 threads (4 waves), 35 KB LDS -> 4 blocks/CU: 16 waves/CU with 4
// independent barrier domains, hiding chunk-boundary drains. nt feat loads
// (L3 bypass). Best measured configuration (r21: 233 us total).
__global__ __launch_bounds__(256) void k_gemm(
    const float* __restrict__ feat_h, const float* __restrict__ feat_p,
    const float* __restrict__ feat_n,
    const s16x8* __restrict__ wsB, const float* __restrict__ bprime,
    const float* __restrict__ aggY, const int* __restrict__ eid,
    const float* __restrict__ Prel, float* __restrict__ out)
{
    __shared__ f32x4 lA[2][64 * 17];      // 2 x 17,408 B padded A chunk dbuf
    __shared__ float lbp[32];

    const int tid  = threadIdx.x;
    const int lane = tid & 63;
    const int w    = tid >> 6;            // wave 0..3
    const int bid  = blockIdx.x;          // 0..1023
    const int tile = (bid & 7) * 128 + (bid >> 3);  // XCD-contiguous (bijective)
    const int e0   = tile << 6;           // 64 entities per block

    const int l15 = lane & 15;
    const int kq  = lane >> 4;

    if (tid < 32) lbp[tid] = bprime[tid];

    const int srow = tid >> 4;            // 0..15
    const int scol = tid & 15;            // f32x4 slot within 256B chunk-row
    const s16x8* wsl = wsB + lane;
    const int rowA = (w << 4) + l15;      // 0..63

    f32x4 aH0 = {0.f,0.f,0.f,0.f}, aH1 = {0.f,0.f,0.f,0.f};
    f32x4 aP0 = {0.f,0.f,0.f,0.f}, aP1 = {0.f,0.f,0.f,0.f};
    f32x4 aN0 = {0.f,0.f,0.f,0.f}, aN1 = {0.f,0.f,0.f,0.f};

#define NTL(P) __builtin_nontemporal_load(P)

#define GEMM_SET(FEATP, A0, A1) do { \
    const f32x4* gs0 = reinterpret_cast<const f32x4*>((FEATP) + (size_t)(e0 + srow)      * FEATD) + scol; \
    const f32x4* gs1 = reinterpret_cast<const f32x4*>((FEATP) + (size_t)(e0 + 16 + srow) * FEATD) + scol; \
    const f32x4* gs2 = reinterpret_cast<const f32x4*>((FEATP) + (size_t)(e0 + 32 + srow) * FEATD) + scol; \
    const f32x4* gs3 = reinterpret_cast<const f32x4*>((FEATP) + (size_t)(e0 + 48 + srow) * FEATD) + scol; \
    f32x4 r0 = NTL(gs0), r1 = NTL(gs1), r2 = NTL(gs2), r3 = NTL(gs3); \
    lA[0][(srow     ) * 17 + scol] = r0; \
    lA[0][(srow + 16) * 17 + scol] = r1; \
    lA[0][(srow + 32) * 17 + scol] = r2; \
    lA[0][(srow + 48) * 17 + scol] = r3; \
    r0 = NTL(gs0 + 16); r1 = NTL(gs1 + 16); r2 = NTL(gs2 + 16); r3 = NTL(gs3 + 16); \
    __syncthreads(); \
    for (int c = 0; c < 12; ++c) { \
        if (c < 11) { \
            lA[(c + 1) & 1][(srow     ) * 17 + scol] = r0; \
            lA[(c + 1) & 1][(srow + 16) * 17 + scol] = r1; \
            lA[(c + 1) & 1][(srow + 32) * 17 + scol] = r2; \
            lA[(c + 1) & 1][(srow + 48) * 17 + scol] = r3; \
            if (c < 10) { \
                r0 = NTL(gs0 + (c + 2) * 16); r1 = NTL(gs1 + (c + 2) * 16); \
                r2 = NTL(gs2 + (c + 2) * 16); r3 = NTL(gs3 + (c + 2) * 16); \
            } \
        } \
        _Pragma("unroll") \
        for (int s = 0; s < 2; ++s) { \
            const int kk = c * 2 + s; \
            const f32x4 fa0 = lA[c & 1][rowA * 17 + s * 8 + kq * 2]; \
            const f32x4 fa1 = lA[c & 1][rowA * 17 + s * 8 + kq * 2 + 1]; \
            s16x8 av; \
            av[0] = f2bf(fa0.x); av[1] = f2bf(fa0.y); av[2] = f2bf(fa0.z); av[3] = f2bf(fa0.w); \
            av[4] = f2bf(fa1.x); av[5] = f2bf(fa1.y); av[6] = f2bf(fa1.z); av[7] = f2bf(fa1.w); \
            const s16x8 wb0 = wsl[(kk * 2 + 0) << 6]; \
            const s16x8 wb1 = wsl[(kk * 2 + 1) << 6]; \
            A0 = __builtin_amdgcn_mfma_f32_16x16x32_bf16(av, wb0, A0, 0, 0, 0); \
            A1 = __builtin_amdgcn_mfma_f32_16x16x32_bf16(av, wb1, A1, 0, 0, 0); \
        } \
        __syncthreads(); \
    } \
} while (0)

    GEMM_SET(feat_h, aH0, aH1);
    GEMM_SET(feat_p, aP0, aP1);
    GEMM_SET(feat_n, aN0, aN1);

#undef GEMM_SET
#undef NTL

    const float bp0 = lbp[l15], bp1 = lbp[l15 + 16];
    const int rbase = e0 + (w << 4) + (kq << 2);

#define NORM1(A0_, A1_, SOFF, Y0_, Y1_) do { \
    float v0 = (A0_)[e] + bp0 + aggY[(SOFF) + eoff + l15]; \
    float v1 = (A1_)[e] + bp1 + aggY[(SOFF) + eoff + l15 + 16]; \
    float sq = v0 * v0 + v1 * v1; \
    sq += __shfl_xor(sq, 1); sq += __shfl_xor(sq, 2); \
    sq += __shfl_xor(sq, 4); sq += __shfl_xor(sq, 8); \
    const float inv = 1.f / fmaxf(sqrtf(sq), 1e-12f); \
    Y0_ = v0 * inv; Y1_ = v1 * inv; \
} while (0)

    #pragma unroll
    for (int e = 0; e < 4; ++e) {
        const int ent = rbase + e;
        const size_t eoff = (size_t)ent * 32;
        float yh0, yh1, yp0, yp1, yn0, yn1;
        NORM1(aH0, aH1, (size_t)0,           yh0, yh1);
        NORM1(aP0, aP1, (size_t)NB * 32,     yp0, yp1);
        NORM1(aN0, aN1, (size_t)2 * NB * 32, yn0, yn1);
        const int ev = eid[ent];
        const float r0 = Prel[(size_t)ev * 32 + l15];
        const float r1 = Prel[(size_t)ev * 32 + l15 + 16];
        const float dp0 = yh0 + r0 - yp0, dp1 = yh1 + r1 - yp1;
        const float dn0 = yh0 + r0 - yn0, dn1 = yh1 + r1 - yn1;
        float sp = dp0 * dp0 + dp1 * dp1;
        float sn = dn0 * dn0 + dn1 * dn1;
        sp += __shfl_xor(sp, 1); sn += __shfl_xor(sn, 1);
        sp += __shfl_xor(sp, 2); sn += __shfl_xor(sn, 2);
        sp += __shfl_xor(sp, 4); sn += __shfl_xor(sn, 4);
        sp += __shfl_xor(sp, 8); sn += __shfl_xor(sn, 8);
        if (l15 == 0) { out[ent] = sqrtf(sp); out[NB + ent] = sqrtf(sn); }
    }
#undef NORM1
}

extern "C" void kernel_launch(void* const* d_in, const int* in_sizes, int n_in,
                              void* d_out, int out_size, void* d_ws, size_t ws_size,
                              hipStream_t stream)
{
    const float* feat_h = (const float*)d_in[6];
    const float* feat_p = (const float*)d_in[13];
    const float* feat_n = (const float*)d_in[20];
    const int*   eid    = (const int*)d_in[21];
    const float* rel_emb = (const float*)d_in[22];
    const float* W_in  = (const float*)d_in[23];
    const float* b_in  = (const float*)d_in[24];
    const float* W_out = (const float*)d_in[25];
    const float* b_out = (const float*)d_in[26];
    const float* W_ent = (const float*)d_in[27];
    const float* b_ent = (const float*)d_in[28];
    const float* W_rel = (const float*)d_in[29];
    const float* b_rel = (const float*)d_in[30];

    char* ws = (char*)d_ws;
    const size_t AGG_B   = (size_t)3 * NB * 32 * 4;          // 25,165,824
    const size_t BINS_B  = (size_t)6 * NBUK * CAP * 8;       // 56,623,104
    const size_t CURS_B  = 8192;
    const size_t PCAT_B  = (size_t)2 * N_RELS * 32 * 4;
    const size_t PREL_B  = (size_t)N_RELS * 32 * 4;
    const size_t BPR_B   = 128;
    const size_t WSB_B   = (size_t)24 * 2 * 64 * 16;
    const bool fast = ws_size >= AGG_B + BINS_B + CURS_B
                                + PCAT_B + PREL_B + BPR_B + WSB_B;

    float* aggY = (float*)ws;
    size_t off = AGG_B;
    uint2* bins = nullptr; unsigned* cursor = nullptr;
    if (fast) {
        bins   = (uint2*)(ws + off);    off += BINS_B;
        cursor = (unsigned*)(ws + off); off += CURS_B;
    }
    float* Pcat   = (float*)(ws + off); off += PCAT_B;
    float* Prel   = (float*)(ws + off); off += PREL_B;
    float* bprime = (float*)(ws + off); off += BPR_B;
    s16x8* wsB    = (s16x8*)(ws + off);

    k_prep<<<(3 * N_RELS + 7) / 8, 256, 0, stream>>>(rel_emb, W_in, b_in, W_out, b_out,
                                                     W_ent, b_ent, W_rel, b_rel,
                                                     Pcat, Prel, bprime, cursor);
    k_wfrag<<<12, 256, 0, stream>>>(W_ent, wsB);

    static const int base_idx[6] = {0, 3, 7, 10, 14, 17};
    if (fast) {
        Mats m;
        for (int i = 0; i < 6; ++i) {
            m.rows[i] = (const int*)d_in[base_idx[i]];
            m.cols[i] = (const int*)d_in[base_idx[i] + 1];
            m.vals[i] = (const float*)d_in[base_idx[i] + 2];
        }
        k_bin<<<6 * 256, 512, 0, stream>>>(m, bins, cursor);
        k_fuse<<<3 * 256, 512, 0, stream>>>(bins, cursor, Pcat, aggY);
    } else {
        hipMemsetAsync(aggY, 0, AGG_B, stream);
        for (int mm = 0; mm < 6; ++mm) {
            const int d = mm & 1, s = mm >> 1;
            k_scatter<<<32768, 256, 0, stream>>>((const int*)d_in[base_idx[mm]],
                                                 (const int*)d_in[base_idx[mm] + 1],
                                                 (const float*)d_in[base_idx[mm] + 2],
                                                 Pcat + (size_t)d * N_RELS * 32,
                                                 aggY + (size_t)s * NB * 32);
        }
    }

    k_gemm<<<1024, 256, 0, stream>>>(feat_h, feat_p, feat_n, wsB, bprime,
                                     aggY, eid, Prel, (float*)d_out);
}